// Round 14
// baseline (76.344 us; speedup 1.0000x reference)
//
#include <hip/hip_runtime.h>
#include <math.h>

// SWALP global block-quantize, R14: sampled-exponent direct quantize + verify.
//   k0: 65536 strided samples (every 196th float4; 262144 floats, ~4 MB lines)
//       -> per-block max -> ws2[256]. P(sample misses global pow2 bucket) ~ 6e-8.
//   k1: wave-reduce ws2 -> Ms; e_s = exp_floor(Ms); quantize EVERYTHING with
//       e_s in R4's proven structure (2048-block grid-stride, reverse order,
//       nt stores, no barrier on store path); running block max -> partial[b].
//       Bit-exact wherever bucket(Ms) == bucket(global max).
//   k2a: 1 block: Mg = reduce(partial), flag = bucket(Ms) != bucket(Mg).
//   k2b: if flag: full requantize with e_g (never for this input; correctness
//        net for any input). Deterministic: no atomics, pure function of input.
// Traffic: ~4 + 205.5R + 205.5W ≈ 415 MB.

#define NT 256
#define NB0 256                  // sample blocks
#define SAMPLE_STRIDE 196        // float4 stride; 65536*196 <= n4
#define NB1 2048                 // main kernel blocks (grid-stride)
#define MG_SLOT 260
#define FLAG_SLOT 261
#define GRID1 2048               // fallback grid

typedef float v4f __attribute__((ext_vector_type(4)));

__device__ inline int exp_floor(float m) {          // floor(log2|m|), floored at -120
    int eb = (int)((__float_as_uint(m) >> 23) & 0xff);
    int e = (eb == 0) ? -120 : eb - 127;
    return max(-120, min(127, e));
}
__device__ inline float exp2i(int k) {              // 2^k, k in [-126,127]
    return __uint_as_float((unsigned)(k + 127) << 23);
}
__device__ inline float absmax4(v4f v) {
    return fmaxf(fmaxf(fabsf(v.x), fabsf(v.y)), fmaxf(fabsf(v.z), fabsf(v.w)));
}
__device__ inline v4f quant4(v4f v, float s, float inv) {
    float a = fminf(fmaxf(rintf(v.x * s), -128.0f), 127.0f);
    float b = fminf(fmaxf(rintf(v.y * s), -128.0f), 127.0f);
    float c = fminf(fmaxf(rintf(v.z * s), -128.0f), 127.0f);
    float d = fminf(fmaxf(rintf(v.w * s), -128.0f), 127.0f);
    v4f r;
    r.x = a * inv; r.y = b * inv; r.z = c * inv; r.w = d * inv;
    return r;
}
__device__ inline float block_max_reduce(float m, int t) {
    __shared__ float sm[4];
    __syncthreads();                                 // safe for repeated use
    #pragma unroll
    for (int off = 32; off > 0; off >>= 1)
        m = fmaxf(m, __shfl_xor(m, off, 64));
    if ((t & 63) == 0) sm[t >> 6] = m;
    __syncthreads();
    return fmaxf(fmaxf(sm[0], sm[1]), fmaxf(sm[2], sm[3]));
}

__global__ __launch_bounds__(NT) void bq_sample(const float* __restrict__ x,
                                                float* __restrict__ ws2) {
    const v4f* __restrict__ x4 = (const v4f*)x;
    const int gtid = blockIdx.x * NT + threadIdx.x;   // 65536 threads
    float m = absmax4(x4[(size_t)gtid * SAMPLE_STRIDE]);
    const float mb = block_max_reduce(m, threadIdx.x);
    if (threadIdx.x == 0) ws2[blockIdx.x] = mb;
}

__global__ __launch_bounds__(NT) void bq_main(const float* __restrict__ x,
                                              float* __restrict__ out,
                                              float* __restrict__ partial,
                                              const float* __restrict__ ws2,
                                              int n4) {
    const int t = threadIdx.x, lane = t & 63;
    // wave-level reduce of the 256 sample maxes -> Ms (no barrier needed)
    float msv = fmaxf(fmaxf(ws2[lane], ws2[lane + 64]),
                      fmaxf(ws2[lane + 128], ws2[lane + 192]));
    #pragma unroll
    for (int off = 32; off > 0; off >>= 1)
        msv = fmaxf(msv, __shfl_xor(msv, off, 64));
    const int es = exp_floor(msv);
    const float s = exp2i(6 - es), inv = exp2i(es - 6);

    const v4f* __restrict__ x4 = (const v4f*)x;
    v4f* __restrict__ o4 = (v4f*)out;
    const int tid = blockIdx.x * NT + t;
    const int T = NB1 * NT;
    const int C = (n4 + T - 1) / T;

    float m = 0.0f;
    for (int c = C - 1; c >= 0; --c) {               // reverse: LLC-recency friendly
        int i = c * T + tid;
        if (i < n4) {
            v4f v = x4[i];
            m = fmaxf(m, absmax4(v));
            __builtin_nontemporal_store(quant4(v, s, inv), &o4[i]);
        }
    }
    const float mb = block_max_reduce(m, t);
    if (t == 0) partial[blockIdx.x] = mb;
}

__global__ __launch_bounds__(NT) void bq_check(const float* __restrict__ partial,
                                               float* __restrict__ ws2) {
    const int t = threadIdx.x;
    float g = 0.0f;
    #pragma unroll
    for (int k = 0; k < NB1 / NT; ++k)
        g = fmaxf(g, partial[t + k * NT]);
    const float mg = block_max_reduce(g, t);
    const float ms = block_max_reduce(ws2[t], t);    // 256 sample maxes
    if (t == 0) {
        ws2[MG_SLOT] = mg;
        ws2[FLAG_SLOT] = (exp_floor(ms) != exp_floor(mg)) ? 1.0f : 0.0f;
    }
}

__global__ __launch_bounds__(NT) void bq_fixall(const float* __restrict__ x,
                                                float* __restrict__ out,
                                                const float* __restrict__ ws2,
                                                int n4) {
    if (ws2[FLAG_SLOT] == 0.0f) return;              // expected path: exit
    const float mg = ws2[MG_SLOT];
    if (mg == 0.0f) return;                          // all-zero input: out==0==ref
    const int eg = exp_floor(mg);
    const float s = exp2i(6 - eg), inv = exp2i(eg - 6);
    const v4f* __restrict__ x4 = (const v4f*)x;
    v4f* __restrict__ o4 = (v4f*)out;
    const int tid = blockIdx.x * NT + threadIdx.x;
    for (int i = tid; i < n4; i += NB1 * NT)
        __builtin_nontemporal_store(quant4(x4[i], s, inv), &o4[i]);
}

// ---------------- fallback: proven R4 two-pass ----------------

__global__ __launch_bounds__(256) void bq_absmax(const float* __restrict__ x,
                                                 float* __restrict__ partial,
                                                 int n) {
    const int n4 = n >> 2;
    const v4f* __restrict__ x4 = (const v4f*)x;
    int tid = blockIdx.x * blockDim.x + threadIdx.x;
    int stride = gridDim.x * blockDim.x;
    float m = 0.0f;
    for (int i = tid; i < n4; i += stride) m = fmaxf(m, absmax4(x4[i]));
    for (int i = (n4 << 2) + tid; i < n; i += stride) m = fmaxf(m, fabsf(x[i]));
    const float mb = block_max_reduce(m, threadIdx.x);
    if (threadIdx.x == 0) partial[blockIdx.x] = mb;
}

__global__ __launch_bounds__(256) void bq_quant(const float* __restrict__ x,
                                                float* __restrict__ out,
                                                const float* __restrict__ partial,
                                                int n) {
    float bm = 0.0f;
    #pragma unroll
    for (int k = 0; k < GRID1 / 256; ++k)
        bm = fmaxf(bm, partial[threadIdx.x + k * 256]);
    const float maxe = block_max_reduce(bm, threadIdx.x);

    const int n4 = n >> 2;
    const v4f* __restrict__ x4 = (const v4f*)x;
    v4f* __restrict__ o4 = (v4f*)out;
    const int tid = blockIdx.x * blockDim.x + threadIdx.x;
    const int T = gridDim.x * blockDim.x;

    if (maxe == 0.0f) {
        for (int i = tid; i < n4; i += T)
            __builtin_nontemporal_store(x4[i], &o4[i]);
        for (int i = (n4 << 2) + tid; i < n; i += T) out[i] = x[i];
        return;
    }
    int e = ilogbf(maxe);
    e = max(-128, min(127, e));
    const float scale    = ldexpf(1.0f, -e + 6);
    const float invscale = ldexpf(1.0f, e - 6);
    for (int i = tid; i < n4; i += T)
        __builtin_nontemporal_store(quant4(x4[i], scale, invscale), &o4[i]);
    for (int i = (n4 << 2) + tid; i < n; i += T) {
        float a = rintf(x[i] * scale);
        a = fminf(fmaxf(a, -128.0f), 127.0f);
        out[i] = a * invscale;
    }
}

extern "C" void kernel_launch(void* const* d_in, const int* in_sizes, int n_in,
                              void* d_out, int out_size, void* d_ws, size_t ws_size,
                              hipStream_t stream) {
    const float* x = (const float*)d_in[0];
    float* out = (float*)d_out;
    int n = in_sizes[0];
    const int n4 = n >> 2;

    // ws layout: [partial: NB1 floats][ws2: 256+8 floats]
    float* partial = (float*)d_ws;
    float* ws2 = partial + NB1;
    const size_t need = (size_t)(NB1 + 264) * sizeof(float);

    if ((n & 3) == 0 && n4 >= NB0 * NT * SAMPLE_STRIDE && ws_size >= need) {
        hipLaunchKernelGGL(bq_sample, dim3(NB0), dim3(NT), 0, stream, x, ws2);
        hipLaunchKernelGGL(bq_main,   dim3(NB1), dim3(NT), 0, stream, x, out, partial, ws2, n4);
        hipLaunchKernelGGL(bq_check,  dim3(1),   dim3(NT), 0, stream, partial, ws2);
        hipLaunchKernelGGL(bq_fixall, dim3(NB1), dim3(NT), 0, stream, x, out, ws2, n4);
    } else {
        hipLaunchKernelGGL(bq_absmax, dim3(GRID1), dim3(256), 0, stream, x, partial, n);
        hipLaunchKernelGGL(bq_quant,  dim3(GRID1), dim3(256), 0, stream, x, out, partial, n);
    }
}

// Round 15
// 74.994 us; speedup vs baseline: 1.0180x; 1.0180x over previous
//
#include <hip/hip_runtime.h>
#include <math.h>

// SWALP global block-quantize, R15: sampled-exponent + slice layout + MALL-bypass.
//   k0: 65536 samples (every 196th float4, exact span) -> per-block max -> ws2[256].
//   k1: 7168 blocks x contiguous 1792-float4 slices (CH=7/thread). e_s from ws2
//       via pure-shuffle wave reduce (no LDS/barrier before stores). Quantize with
//       e_s, store via asm sc0 sc1 nt (system no-allocate: keep x LLC-resident).
//       Running block max -> partial[b] (reduced AFTER stores are issued).
//   k2a: 1 block: Mg = reduce(partial[7168]), Ms = reduce(ws2), flag on bucket
//        mismatch (P ~ 6e-8 for N(0,1); correctness net for any input).
//   k2b: flag ? full requantize with e_g : immediate exit. Deterministic.
// Traffic: ~4 + 205.5R(partially LLC) + 205.5W.

#define NT 256
#define NB0 256                  // sample blocks
#define SAMPLE_STRIDE 196        // 65536 * 196 == n4 exactly
#define NB 7168                  // main blocks; NB*NT*CH == n4
#define CH 7                     // float4 per thread
#define MG_SLOT 256              // ws2 slots after the 256 sample maxes
#define FLAG_SLOT 257
#define GRID1 2048               // fallback grid

typedef float v4f __attribute__((ext_vector_type(4)));

__device__ inline void store_stream(v4f* p, v4f v) {
    asm volatile("global_store_dwordx4 %0, %1, off sc0 sc1 nt" :: "v"(p), "v"(v));
}
__device__ inline int exp_floor(float m) {          // floor(log2|m|), floored at -120
    int eb = (int)((__float_as_uint(m) >> 23) & 0xff);
    int e = (eb == 0) ? -120 : eb - 127;
    return max(-120, min(127, e));
}
__device__ inline float exp2i(int k) {              // 2^k, k in [-126,127]
    return __uint_as_float((unsigned)(k + 127) << 23);
}
__device__ inline float absmax4(v4f v) {
    return fmaxf(fmaxf(fabsf(v.x), fabsf(v.y)), fmaxf(fabsf(v.z), fabsf(v.w)));
}
__device__ inline v4f quant4(v4f v, float s, float inv) {
    float a = fminf(fmaxf(rintf(v.x * s), -128.0f), 127.0f);
    float b = fminf(fmaxf(rintf(v.y * s), -128.0f), 127.0f);
    float c = fminf(fmaxf(rintf(v.z * s), -128.0f), 127.0f);
    float d = fminf(fmaxf(rintf(v.w * s), -128.0f), 127.0f);
    v4f r;
    r.x = a * inv; r.y = b * inv; r.z = c * inv; r.w = d * inv;
    return r;
}
__device__ inline float wave_max(float m) {
    #pragma unroll
    for (int off = 32; off > 0; off >>= 1)
        m = fmaxf(m, __shfl_xor(m, off, 64));
    return m;
}
__device__ inline float block_max_reduce(float m, int t) {
    __shared__ float sm[4];
    m = wave_max(m);
    if ((t & 63) == 0) sm[t >> 6] = m;
    __syncthreads();
    return fmaxf(fmaxf(sm[0], sm[1]), fmaxf(sm[2], sm[3]));
}

__global__ __launch_bounds__(NT) void bq_sample(const float* __restrict__ x,
                                                float* __restrict__ ws2) {
    const v4f* __restrict__ x4 = (const v4f*)x;
    const int gtid = blockIdx.x * NT + threadIdx.x;   // 65536 threads
    float m = absmax4(x4[(size_t)gtid * SAMPLE_STRIDE]);
    const float mb = block_max_reduce(m, threadIdx.x);
    if (threadIdx.x == 0) ws2[blockIdx.x] = mb;
}

__global__ __launch_bounds__(NT) void bq_spec(const float* __restrict__ x,
                                              float* __restrict__ out,
                                              float* __restrict__ partial,
                                              const float* __restrict__ ws2) {
    const int t = threadIdx.x, lane = t & 63;
    // Ms via pure-shuffle wave reduce of ws2[256] (no LDS, no barrier)
    float msv = fmaxf(fmaxf(ws2[lane], ws2[lane + 64]),
                      fmaxf(ws2[lane + 128], ws2[lane + 192]));
    msv = wave_max(msv);
    const int es = exp_floor(msv);
    const float s = exp2i(6 - es), inv = exp2i(es - 6);

    const v4f* __restrict__ x4 = (const v4f*)x + (size_t)blockIdx.x * (NT * CH);
    v4f* __restrict__ o4 = (v4f*)out + (size_t)blockIdx.x * (NT * CH);

    float m = 0.0f;
    #pragma unroll
    for (int k = 0; k < CH; ++k) {
        v4f v = x4[k * NT + t];
        m = fmaxf(m, absmax4(v));
        store_stream(&o4[k * NT + t], quant4(v, s, inv));
    }
    const float mb = block_max_reduce(m, t);          // after stores issued
    if (t == 0) partial[blockIdx.x] = fmaxf(mb, msv);
}

__global__ __launch_bounds__(NT) void bq_check(const float* __restrict__ partial,
                                               float* __restrict__ ws2) {
    const int t = threadIdx.x;
    float g = 0.0f;
    #pragma unroll
    for (int k = 0; k < NB / NT; ++k)
        g = fmaxf(g, partial[t + k * NT]);
    const float mg = block_max_reduce(g, t);
    __syncthreads();                                  // reuse of LDS in reduce
    const float ms = block_max_reduce(ws2[t], t);
    if (t == 0) {
        ws2[MG_SLOT] = mg;
        ws2[FLAG_SLOT] = (exp_floor(ms) != exp_floor(mg)) ? 1.0f : 0.0f;
    }
}

__global__ __launch_bounds__(NT) void bq_fixall(const float* __restrict__ x,
                                                float* __restrict__ out,
                                                const float* __restrict__ ws2) {
    if (ws2[FLAG_SLOT] == 0.0f) return;              // expected path
    const float mg = ws2[MG_SLOT];
    if (mg == 0.0f) return;                          // all-zero: out==0==ref
    const int eg = exp_floor(mg);
    const float s = exp2i(6 - eg), inv = exp2i(eg - 6);
    const int t = threadIdx.x;
    const v4f* __restrict__ x4 = (const v4f*)x + (size_t)blockIdx.x * (NT * CH);
    v4f* __restrict__ o4 = (v4f*)out + (size_t)blockIdx.x * (NT * CH);
    #pragma unroll
    for (int k = 0; k < CH; ++k)
        store_stream(&o4[k * NT + t], quant4(x4[k * NT + t], s, inv));
}

// ---------------- fallback: proven R4 two-pass ----------------

__global__ __launch_bounds__(256) void bq_absmax(const float* __restrict__ x,
                                                 float* __restrict__ partial,
                                                 int n) {
    const int n4 = n >> 2;
    const v4f* __restrict__ x4 = (const v4f*)x;
    int tid = blockIdx.x * blockDim.x + threadIdx.x;
    int stride = gridDim.x * blockDim.x;
    float m = 0.0f;
    for (int i = tid; i < n4; i += stride) m = fmaxf(m, absmax4(x4[i]));
    for (int i = (n4 << 2) + tid; i < n; i += stride) m = fmaxf(m, fabsf(x[i]));
    const float mb = block_max_reduce(m, threadIdx.x);
    if (threadIdx.x == 0) partial[blockIdx.x] = mb;
}

__global__ __launch_bounds__(256) void bq_quant(const float* __restrict__ x,
                                                float* __restrict__ out,
                                                const float* __restrict__ partial,
                                                int n) {
    float bm = 0.0f;
    #pragma unroll
    for (int k = 0; k < GRID1 / 256; ++k)
        bm = fmaxf(bm, partial[threadIdx.x + k * 256]);
    const float maxe = block_max_reduce(bm, threadIdx.x);

    const int n4 = n >> 2;
    const v4f* __restrict__ x4 = (const v4f*)x;
    v4f* __restrict__ o4 = (v4f*)out;
    const int tid = blockIdx.x * blockDim.x + threadIdx.x;
    const int T = gridDim.x * blockDim.x;

    if (maxe == 0.0f) {
        for (int i = tid; i < n4; i += T)
            __builtin_nontemporal_store(x4[i], &o4[i]);
        for (int i = (n4 << 2) + tid; i < n; i += T) out[i] = x[i];
        return;
    }
    int e = ilogbf(maxe);
    e = max(-128, min(127, e));
    const float scale    = ldexpf(1.0f, -e + 6);
    const float invscale = ldexpf(1.0f, e - 6);
    for (int i = tid; i < n4; i += T)
        __builtin_nontemporal_store(quant4(x4[i], scale, invscale), &o4[i]);
    for (int i = (n4 << 2) + tid; i < n; i += T) {
        float a = rintf(x[i] * scale);
        a = fminf(fmaxf(a, -128.0f), 127.0f);
        out[i] = a * invscale;
    }
}

extern "C" void kernel_launch(void* const* d_in, const int* in_sizes, int n_in,
                              void* d_out, int out_size, void* d_ws, size_t ws_size,
                              hipStream_t stream) {
    const float* x = (const float*)d_in[0];
    float* out = (float*)d_out;
    int n = in_sizes[0];
    const int n4 = n >> 2;

    // ws layout: [partial: NB floats][ws2: 256+8 floats]
    float* partial = (float*)d_ws;
    float* ws2 = partial + NB;
    const size_t need = (size_t)(NB + 264) * sizeof(float);

    if (n4 == NB * NT * CH && ws_size >= need) {
        hipLaunchKernelGGL(bq_sample, dim3(NB0), dim3(NT), 0, stream, x, ws2);
        hipLaunchKernelGGL(bq_spec,   dim3(NB),  dim3(NT), 0, stream, x, out, partial, ws2);
        hipLaunchKernelGGL(bq_check,  dim3(1),   dim3(NT), 0, stream, partial, ws2);
        hipLaunchKernelGGL(bq_fixall, dim3(NB),  dim3(NT), 0, stream, x, out, ws2);
    } else {
        hipLaunchKernelGGL(bq_absmax, dim3(GRID1), dim3(256), 0, stream, x, partial, n);
        hipLaunchKernelGGL(bq_quant,  dim3(GRID1), dim3(256), 0, stream, x, out, partial, n);
    }
}